// Round 9
// baseline (456.429 us; speedup 1.0000x reference)
//
#include <hip/hip_runtime.h>
#include <hip/hip_bf16.h>

#define BATCH 8
#define CIN   128
#define HH    256
#define WW    256
#define OUTC  64
#define INCH  1152   // CIN*9
#define HW    (HH*WW)

#define ROWB       ((size_t)WW * CIN * 2)                 // 65536 B per xT row
#define XT_BYTES   ((size_t)BATCH * HH * WW * CIN * 2)    // 134217728
#define WMOD_BYTES ((size_t)BATCH * 9 * OUTC * CIN * 2)   // 1179648
#define Z_BYTES    ((size_t)4 * ROWB)                     // 262144 zero region

typedef __attribute__((ext_vector_type(8))) short short8;
typedef __attribute__((ext_vector_type(4))) float f32x4;
typedef __attribute__((ext_vector_type(4))) unsigned int u32x4;

__device__ __forceinline__ unsigned short bf16r(float f) {
    unsigned u = __builtin_bit_cast(unsigned, f);
    u += 0x7fffu + ((u >> 16) & 1u);
    return (unsigned short)(u >> 16);
}

// wmod[b][tap][o][c] = bf16(weight[o][c*9+tap] * style[b][c*9+tap])
__global__ void __launch_bounds__(256) wmod_kernel(const float* __restrict__ weight,
                                                   const float* __restrict__ style,
                                                   unsigned short* __restrict__ wmod) {
    int i = blockIdx.x * 256 + threadIdx.x;
    if (i >= BATCH * 9 * OUTC * CIN) return;
    int c    = i & (CIN - 1);
    int rest = i >> 7;
    int o    = rest & (OUTC - 1);
    int bt   = rest >> 6;          // b*9 + tap
    int tap  = bt % 9;
    int b    = bt / 9;
    int k    = c * 9 + tap;
    float v = weight[o * INCH + k] * style[b * INCH + k];
    wmod[i] = bf16r(v);
}

// xT[b][h][w][c] = bf16(x[b][c][h][w]).  Lane = w (coalesced 256B reads per
// c-row); thread owns 32 channels -> one full 64B-sector write per pixel.
__global__ void __launch_bounds__(256) transpose_kernel(const float* __restrict__ x,
                                                        unsigned short* __restrict__ xT) {
    const int w  = blockIdx.x * 64 + (threadIdx.x & 63);
    const int c0 = (threadIdx.x >> 6) * 32;
    const int h  = blockIdx.y;
    const int b  = blockIdx.z;

    const float* xp = x + ((size_t)(b * CIN + c0)) * HW + h * WW + w;
    unsigned short* op = xT + ((size_t)(b * HH + h) * WW + w) * CIN + c0;

    float f[32];
#pragma unroll
    for (int j = 0; j < 32; ++j) f[j] = xp[(size_t)j * HW];

    unsigned pk[16];
#pragma unroll
    for (int j = 0; j < 16; ++j)
        pk[j] = (unsigned)bf16r(f[2 * j]) | ((unsigned)bf16r(f[2 * j + 1]) << 16);

#pragma unroll
    for (int u = 0; u < 4; ++u) {
        u32x4 v = {pk[u * 4 + 0], pk[u * 4 + 1], pk[u * 4 + 2], pk[u * 4 + 3]};
        *(u32x4*)(op + u * 8) = v;
    }
}

// -------- barrier-free conv: B-fragments straight from xT (NHWC bf16) -------
// Block: 256 threads = 4 waves; tile 64o x (2h x 64w) px.
// Wave (wr=wv>>1, wc=wv&1): 32o x (2h x 32w) px; acc[2][4] = 32 f32/lane.
// No LDS, no __syncthreads: per chunk-tap each lane does 2 A-loads (wmod,
// L2-hot) + 4 B-loads (xT, 16B contiguous, L1-reused 9x across taps) + 8 MFMA.
// Halo: w-OOB -> per-lane pointer into 256KB zero region (set at p6 build);
// h-OOB -> wave-uniform base select per (ni,kh). dr*ROWB stays inside the
// 4-row zero region for all dr in [-1,2] and chunk offsets.
__global__ void __launch_bounds__(256, 4) conv3_kernel(
    const unsigned short* __restrict__ xT,
    const unsigned short* __restrict__ wmod,
    const char* __restrict__ zbase,
    float* __restrict__ out)
{
    const int tid = threadIdx.x;           // 0..255
    const int bx  = blockIdx.x;            // 0..511: (h-tile<<2)|w-tile
    const int b   = blockIdx.y;            // batch
    const int h0  = (bx >> 2) * 2;
    const int w0  = (bx & 3) * 64;

    const int wv  = tid >> 6;              // 0..3
    const int wr  = wv >> 1;               // o-half
    const int wc  = wv & 1;                // w-half
    const int l15 = tid & 15;
    const int kg  = (tid >> 4) & 3;

    const char* zmid = zbase + ROWB;       // dr in [-1,2] stays in [0, 4*ROWB)

    // per-lane B base pointers, row h0, chunk 0: (ni&1, kw) -> 6 pointers
    const char* p6[2][3];
#pragma unroll
    for (int i1 = 0; i1 < 2; ++i1)
#pragma unroll
        for (int kw = 0; kw < 3; ++kw) {
            int wn = w0 + wc * 32 + i1 * 16 + l15 + kw - 1;
            bool wok = (unsigned)wn < WW;
            p6[i1][kw] = wok
                ? (const char*)(xT + ((size_t)(b * HH + h0) * WW + wn) * CIN + kg * 8)
                : (zmid + kg * 16);
        }

    f32x4 acc[2][4];
#pragma unroll
    for (int mi = 0; mi < 2; ++mi)
#pragma unroll
        for (int ni = 0; ni < 4; ++ni) acc[mi][ni] = (f32x4){0.f, 0.f, 0.f, 0.f};

#pragma unroll
    for (int chunk = 0; chunk < 4; ++chunk) {
        const unsigned short* wt0 =
            wmod + ((size_t)(b * 9) * OUTC) * CIN + chunk * 32;
#pragma unroll
        for (int tap = 0; tap < 9; ++tap) {
            const int kh = tap / 3, kw = tap % 3;

            short8 A[2];
            const unsigned short* wt = wt0 + (size_t)tap * OUTC * CIN;
#pragma unroll
            for (int mi = 0; mi < 2; ++mi)
                A[mi] = *(const short8*)(wt + (wr * 32 + mi * 16 + l15) * CIN +
                                         kg * 8);

            short8 Bv[4];
#pragma unroll
            for (int ni = 0; ni < 4; ++ni) {
                const int dr = (ni >> 1) + kh - 1;          // -1..2
                const bool hok = (unsigned)(h0 + dr) < HH;  // wave-uniform
                const char* base = hok ? p6[ni & 1][kw] : (zmid + kg * 16);
                Bv[ni] = *(const short8*)(base + (ptrdiff_t)dr * (ptrdiff_t)ROWB +
                                          chunk * 64);
            }
#pragma unroll
            for (int mi = 0; mi < 2; ++mi)
#pragma unroll
                for (int ni = 0; ni < 4; ++ni)
                    acc[mi][ni] = __builtin_amdgcn_mfma_f32_16x16x32_bf16(
                        A[mi], Bv[ni], acc[mi][ni], 0, 0, 0);
        }
    }

    // ---- epilogue: D mapping col=lane&15 (pixel), row=(lane>>4)*4+r (o)
    float* op = out + ((size_t)b * OUTC) * HW;
#pragma unroll
    for (int mi = 0; mi < 2; ++mi) {
#pragma unroll
        for (int ni = 0; ni < 4; ++ni) {
            int h = h0 + (ni >> 1);
            int w = w0 + wc * 32 + (ni & 1) * 16 + l15;
#pragma unroll
            for (int r = 0; r < 4; ++r) {
                int o = wr * 32 + mi * 16 + kg * 4 + r;
                op[(size_t)o * HW + h * WW + w] = acc[mi][ni][r];
            }
        }
    }
}

// ---------------- fallback conv (round-7 path, fp32 staging) ----------------
template <bool GW>
__global__ void __launch_bounds__(512, 4) conv_kernel(
    const float* __restrict__ x,
    const unsigned short* __restrict__ wmod,
    const float* __restrict__ weight,
    const float* __restrict__ style,
    float* __restrict__ out)
{
    __shared__ __align__(16) unsigned short xs_sm[170 * 64];

    const int tid = threadIdx.x;
    const int bx  = blockIdx.x;
    const int b   = blockIdx.y;
    const int h0  = (bx >> 3) * 8;
    const int w0  = (bx & 7) * 32;

    const int wv  = tid >> 6;
    const int wr  = wv >> 2;
    const int wc  = wv & 3;
    const int l15 = tid & 15;
    const int kg  = (tid >> 4) & 3;

    int sbase[4];
#pragma unroll
    for (int ni = 0; ni < 4; ++ni) {
        int p = wc * 64 + ni * 16 + l15;
        sbase[ni] = (p >> 5) * 34 + (p & 31);
    }

    const bool tvalid = tid < 400;
    const int scg = tvalid ? tid / 100 : 0;
    const int srw = tvalid ? tid % 100 : 0;
    const int sr  = srw / 10;
    const int swq = srw % 10;
    const int sh  = h0 - 1 + sr;
    const bool hok = (unsigned)sh < HH;
    const int wload  = w0 - 4 + swq * 4;
    const int wclamp = min(max(wload, 0), WW - 4);
    const int gbase  = (hok ? sh : 0) * WW + wclamp;

    f32x4 acc[2][4];
#pragma unroll
    for (int mi = 0; mi < 2; ++mi)
#pragma unroll
        for (int ni = 0; ni < 4; ++ni) acc[mi][ni] = (f32x4){0.f, 0.f, 0.f, 0.f};

    for (int chunk = 0; chunk < 4; ++chunk) {
        if (chunk) __syncthreads();

        if (tvalid) {
            const float* xp =
                x + ((size_t)(b * CIN + chunk * 32 + scg * 8)) * HW + gbase;
            f32x4 f[8];
#pragma unroll
            for (int j = 0; j < 8; ++j)
                f[j] = hok ? *(const f32x4*)(xp + (size_t)j * HW)
                           : (f32x4){0.f, 0.f, 0.f, 0.f};
#pragma unroll
            for (int u = 0; u < 4; ++u) {
                int w   = wload + u;
                int col = w - (w0 - 1);
                if (col >= 0 && col <= 33) {
                    bool wok = hok && ((unsigned)w < WW);
                    short8 sv;
#pragma unroll
                    for (int j = 0; j < 8; ++j)
                        sv[j] = wok ? (short)bf16r(f[j][u]) : (short)0;
                    int s = sr * 34 + col;
                    int q = s >> 1;
                    int g = (((s & 1) << 2) | scg) ^ (q & 7);
                    *(short8*)&xs_sm[q * 64 + g * 8] = sv;
                }
            }
        }
        __syncthreads();

        const unsigned short* wmb = wmod + ((size_t)(b * 9) * OUTC) * CIN + chunk * 32;
#pragma unroll
        for (int tap = 0; tap < 9; ++tap) {
            const int kh = tap / 3, kw = tap % 3;

            short8 A[2];
            if (GW) {
                const unsigned short* wt = wmb + (size_t)tap * OUTC * CIN;
#pragma unroll
                for (int mi = 0; mi < 2; ++mi)
                    A[mi] = *(const short8*)(wt + (wr * 32 + mi * 16 + l15) * CIN +
                                             kg * 8);
            } else {
#pragma unroll
                for (int mi = 0; mi < 2; ++mi) {
                    int o = wr * 32 + mi * 16 + l15;
#pragma unroll
                    for (int j = 0; j < 8; ++j) {
                        int c = chunk * 32 + kg * 8 + j;
                        int k = c * 9 + tap;
                        A[mi][j] = (short)bf16r(weight[o * INCH + k] *
                                                style[b * INCH + k]);
                    }
                }
            }

            short8 Bv[4];
#pragma unroll
            for (int ni = 0; ni < 4; ++ni) {
                int s = sbase[ni] + kh * 34 + kw;
                int q = s >> 1;
                int g = (((s & 1) << 2) | kg) ^ (q & 7);
                Bv[ni] = *(const short8*)&xs_sm[q * 64 + g * 8];
            }
#pragma unroll
            for (int mi = 0; mi < 2; ++mi)
#pragma unroll
                for (int ni = 0; ni < 4; ++ni)
                    acc[mi][ni] = __builtin_amdgcn_mfma_f32_16x16x32_bf16(
                        A[mi], Bv[ni], acc[mi][ni], 0, 0, 0);
        }
    }

    float* op = out + ((size_t)b * OUTC) * HW;
#pragma unroll
    for (int mi = 0; mi < 2; ++mi) {
#pragma unroll
        for (int ni = 0; ni < 4; ++ni) {
            int p = wc * 64 + ni * 16 + l15;
            int h = h0 + (p >> 5), w = w0 + (p & 31);
#pragma unroll
            for (int r = 0; r < 4; ++r) {
                int o = wr * 32 + mi * 16 + kg * 4 + r;
                op[(size_t)o * HW + h * WW + w] = acc[mi][ni][r];
            }
        }
    }
}

extern "C" void kernel_launch(void* const* d_in, const int* in_sizes, int n_in,
                              void* d_out, int out_size, void* d_ws, size_t ws_size,
                              hipStream_t stream) {
    const float* x      = (const float*)d_in[0];
    const float* style  = (const float*)d_in[1];
    const float* weight = (const float*)d_in[2];
    float* out = (float*)d_out;

    const int wmod_total = BATCH * 9 * OUTC * CIN;

    if (ws_size >= XT_BYTES + WMOD_BYTES + Z_BYTES) {
        unsigned short* xT    = (unsigned short*)d_ws;
        unsigned short* wmodp = (unsigned short*)((char*)d_ws + XT_BYTES);
        char*           zbase = (char*)d_ws + XT_BYTES + WMOD_BYTES;

        wmod_kernel<<<(wmod_total + 255) / 256, 256, 0, stream>>>(weight, style, wmodp);
        transpose_kernel<<<dim3(4, HH, BATCH), 256, 0, stream>>>(x, xT);
        hipMemsetAsync(zbase, 0, Z_BYTES, stream);
        conv3_kernel<<<dim3(512, BATCH), 256, 0, stream>>>(xT, wmodp, zbase, out);
    } else if (ws_size >= WMOD_BYTES) {
        unsigned short* wmodp = (unsigned short*)d_ws;
        wmod_kernel<<<(wmod_total + 255) / 256, 256, 0, stream>>>(weight, style, wmodp);
        conv_kernel<true><<<dim3(256, BATCH), 512, 0, stream>>>(
            x, wmodp, nullptr, nullptr, out);
    } else {
        conv_kernel<false><<<dim3(256, BATCH), 512, 0, stream>>>(
            x, nullptr, weight, style, out);
    }
}

// Round 10
// 264.329 us; speedup vs baseline: 1.7267x; 1.7267x over previous
//
#include <hip/hip_runtime.h>
#include <hip/hip_bf16.h>

#define BATCH 8
#define CIN   128
#define HH    256
#define WW    256
#define OUTC  64
#define INCH  1152   // CIN*9
#define HW    (HH*WW)
#define WMOD_BYTES ((size_t)BATCH * 9 * OUTC * CIN * 2)

typedef __attribute__((ext_vector_type(8))) short short8;
typedef __attribute__((ext_vector_type(4))) float f32x4;
typedef __attribute__((ext_vector_type(4), aligned(4))) float f32x4u; // 4B-aligned vec load

__device__ __forceinline__ unsigned short bf16r(float f) {
    unsigned u = __builtin_bit_cast(unsigned, f);
    u += 0x7fffu + ((u >> 16) & 1u);
    return (unsigned short)(u >> 16);
}

// wmod[b][tap][o][c] = bf16(weight[o][c*9+tap] * style[b][c*9+tap])
__global__ void __launch_bounds__(256) wmod_kernel(const float* __restrict__ weight,
                                                   const float* __restrict__ style,
                                                   unsigned short* __restrict__ wmod) {
    int i = blockIdx.x * 256 + threadIdx.x;
    if (i >= BATCH * 9 * OUTC * CIN) return;
    int c    = i & (CIN - 1);
    int rest = i >> 7;
    int o    = rest & (OUTC - 1);
    int bt   = rest >> 6;
    int tap  = bt % 9;
    int b    = bt / 9;
    int k    = c * 9 + tap;
    wmod[i] = bf16r(weight[o * INCH + k] * style[b * INCH + k]);
}

// conv4: wave-autonomous pipeline.
// Block: 128 thr = 2 waves (o-split). Tile: 64o x (4h x 16w) px.
// Wave: 32o x 64px, acc[2][4] = 32 VGPR. A[9][2] = 72 VGPR preloaded/chunk.
// LDS: xs[2][108*32] bf16; addr(s,c) = s*32 + ((c>>3) ^ (s&3))*8 + (c&7),
//   s = hrow*18 + col over 6x18 halo. Double-buffered, pair-barrier only.
// Per chunk k: stageLoad(k+1) [VMEM, oldest] -> compute(k) [LDS+MFMA only,
//   no VMEM -> no vmcnt stall] -> loadA(k+1) [VMEM] -> cvt+write (compiler
//   waits counted vmcnt for g, not draining A) -> __syncthreads (2 waves).
// Halo: LDS pre-zeroed once; OOB rows/cols simply never written.
template <bool GW>
__global__ void __launch_bounds__(128, 2) conv4_kernel(
    const float* __restrict__ x,
    const unsigned short* __restrict__ wmod,
    const float* __restrict__ weight,
    const float* __restrict__ style,
    float* __restrict__ out)
{
    __shared__ __align__(16) unsigned short xs_sm[2][108 * 32];

    const int tid = threadIdx.x;           // 0..127
    const int bx  = blockIdx.x;            // 0..1023: ht*16 + wt
    const int b   = blockIdx.y;
    const int h0  = (bx >> 4) * 4;
    const int w0  = (bx & 15) * 16;

    const int wr  = tid >> 6;              // o-half (wave)
    const int l15 = tid & 15;
    const int kg  = (tid >> 4) & 3;

    // ---- zero LDS once (edge halo correctness relies on this)
    {
        short8 z = {0, 0, 0, 0, 0, 0, 0, 0};
        short8* p = (short8*)&xs_sm[0][0];
        for (int i = tid; i < 2 * 108 * 32 / 8; i += 128) p[i] = z;
    }

    // ---- staging geometry: 120 tasks = (cg 0..3) x (sr 0..5) x (wq 0..4)
    const bool tval = tid < 120;
    const int tt  = tval ? tid : 0;
    const int cg  = tt / 30;
    const int rem = tt % 30;
    const int sr  = rem / 5;
    const int wq  = rem % 5;
    const int sh  = h0 - 1 + sr;
    const bool hok = tval && ((unsigned)sh < HH);
    const int wl  = w0 - 1 + wq * 4;
    const int wlc = min(max(wl, 0), WW - 4);
    const int colbase = wlc - (w0 - 1);    // col of g[.][0]
    const float* xsrc = x + ((size_t)(b * CIN + cg * 8)) * HW +
                        (hok ? sh : 0) * WW + wlc;

    f32x4 acc[2][4];
#pragma unroll
    for (int mi = 0; mi < 2; ++mi)
#pragma unroll
        for (int ni = 0; ni < 4; ++ni) acc[mi][ni] = (f32x4){0.f, 0.f, 0.f, 0.f};

    short8 A[9][2];
    f32x4  g[8];

    auto stageLoad = [&](int chunk) {
        if (hok) {
#pragma unroll
            for (int j = 0; j < 8; ++j)
                g[j] = *(const f32x4u*)(xsrc + (size_t)(chunk * 32 + j) * HW);
        }
    };

    auto stageWrite = [&](unsigned short* buf) {
        if (hok) {
#pragma unroll
            for (int u = 0; u < 4; ++u) {
                int col = colbase + u;
                if (col >= 0 && col <= 17) {
                    int s  = sr * 18 + col;
                    int gr = cg ^ (s & 3);
                    short8 sv;
#pragma unroll
                    for (int j = 0; j < 8; ++j) sv[j] = (short)bf16r(g[j][u]);
                    *(short8*)&buf[s * 32 + gr * 8] = sv;
                }
            }
        }
    };

    auto loadA = [&](int chunk) {
        if (GW) {
            const unsigned short* wb =
                wmod + ((size_t)(b * 9) * OUTC) * CIN + chunk * 32 + kg * 8;
#pragma unroll
            for (int tap = 0; tap < 9; ++tap)
#pragma unroll
                for (int mi = 0; mi < 2; ++mi)
                    A[tap][mi] = *(const short8*)(
                        wb + ((size_t)tap * OUTC + wr * 32 + mi * 16 + l15) * CIN);
        } else {
#pragma unroll
            for (int tap = 0; tap < 9; ++tap)
#pragma unroll
                for (int mi = 0; mi < 2; ++mi) {
                    int o = wr * 32 + mi * 16 + l15;
#pragma unroll
                    for (int j = 0; j < 8; ++j) {
                        int c = chunk * 32 + kg * 8 + j;
                        int k = c * 9 + tap;
                        A[tap][mi][j] = (short)bf16r(weight[o * INCH + k] *
                                                     style[b * INCH + k]);
                    }
                }
        }
    };

    auto compute = [&](const unsigned short* buf) {
#pragma unroll
        for (int kh = 0; kh < 3; ++kh)
#pragma unroll
            for (int kw = 0; kw < 3; ++kw) {
                const int tap = kh * 3 + kw;
                short8 Bv[4];
#pragma unroll
                for (int ni = 0; ni < 4; ++ni) {
                    int s  = (ni + kh) * 18 + (l15 + kw);
                    int gr = kg ^ (s & 3);
                    Bv[ni] = *(const short8*)&buf[s * 32 + gr * 8];
                }
#pragma unroll
                for (int mi = 0; mi < 2; ++mi)
#pragma unroll
                    for (int ni = 0; ni < 4; ++ni)
                        acc[mi][ni] = __builtin_amdgcn_mfma_f32_16x16x32_bf16(
                            A[tap][mi], Bv[ni], acc[mi][ni], 0, 0, 0);
            }
    };

    __syncthreads();                       // LDS zero visible to all

    // ---- prologue: chunk 0
    stageLoad(0);
    loadA(0);
    stageWrite(xs_sm[0]);                  // waits g via counted vmcnt
    __syncthreads();

    // ---- chunk 0
    stageLoad(1);
    __builtin_amdgcn_sched_barrier(0);
    compute(xs_sm[0]);
    __builtin_amdgcn_sched_barrier(0);
    loadA(1);
    stageWrite(xs_sm[1]);
    __syncthreads();

    // ---- chunk 1
    stageLoad(2);
    __builtin_amdgcn_sched_barrier(0);
    compute(xs_sm[1]);
    __builtin_amdgcn_sched_barrier(0);
    loadA(2);
    stageWrite(xs_sm[0]);
    __syncthreads();

    // ---- chunk 2
    stageLoad(3);
    __builtin_amdgcn_sched_barrier(0);
    compute(xs_sm[0]);
    __builtin_amdgcn_sched_barrier(0);
    loadA(3);
    stageWrite(xs_sm[1]);
    __syncthreads();

    // ---- chunk 3
    compute(xs_sm[1]);

    // ---- epilogue: D mapping col=lane&15 (pixel), row=(lane>>4)*4+r (o)
    float* op = out + ((size_t)b * OUTC) * HW + (size_t)h0 * WW + w0 + l15;
#pragma unroll
    for (int mi = 0; mi < 2; ++mi)
#pragma unroll
        for (int ni = 0; ni < 4; ++ni)
#pragma unroll
            for (int rr = 0; rr < 4; ++rr) {
                int o = wr * 32 + mi * 16 + kg * 4 + rr;
                op[(size_t)o * HW + ni * WW] = acc[mi][ni][rr];
            }
}

extern "C" void kernel_launch(void* const* d_in, const int* in_sizes, int n_in,
                              void* d_out, int out_size, void* d_ws, size_t ws_size,
                              hipStream_t stream) {
    const float* x      = (const float*)d_in[0];
    const float* style  = (const float*)d_in[1];
    const float* weight = (const float*)d_in[2];
    float* out = (float*)d_out;

    const int wmod_total = BATCH * 9 * OUTC * CIN;

    if (ws_size >= WMOD_BYTES) {
        unsigned short* wmodp = (unsigned short*)d_ws;
        wmod_kernel<<<(wmod_total + 255) / 256, 256, 0, stream>>>(weight, style, wmodp);
        conv4_kernel<true><<<dim3(1024, BATCH), 128, 0, stream>>>(
            x, wmodp, nullptr, nullptr, out);
    } else {
        conv4_kernel<false><<<dim3(1024, BATCH), 128, 0, stream>>>(
            x, nullptr, weight, style, out);
    }
}